// Round 3
// baseline (1748.935 us; speedup 1.0000x reference)
//
#include <hip/hip_runtime.h>
#include <math.h>

#define NTOK   32768
#define DMODEL 512
#define HIDDEN 2048
#define NEXP   16
#define TM     256             // token-tile (M)
#define MAXT   144             // sum_e ceil(c_e/256) <= 128+15, rounded to mult of 8
#define PADN   (MAXT * TM)
#define CPAD   16              // pad per-expert counters to one 64B line

typedef short bf16x8 __attribute__((ext_vector_type(8)));
typedef float f32x4  __attribute__((ext_vector_type(4)));

__device__ __forceinline__ short f2bf(float f) {
  union { float f; unsigned int u; } v; v.f = f;
  unsigned int r = v.u + 0x7FFFu + ((v.u >> 16) & 1u);   // RNE
  return (short)(r >> 16);
}

__device__ __forceinline__ void gload_lds16(const void* g, void* l) {
  __builtin_amdgcn_global_load_lds(
      (const __attribute__((address_space(1))) void*)g,
      (__attribute__((address_space(3))) void*)l, 16, 0, 0);
}

// tanh-form GELU, overflow-safe. |err| vs exact erf GELU < 4e-4.
__device__ __forceinline__ float gelu_f(float v) {
  const float u = v * (0.7978845608f + 0.0356774081f * v * v);
  const float au = fabsf(u);
  const float z = __expf(-2.0f * au);
  float T = (1.0f - z) / (1.0f + z);
  T = copysignf(T, u);
  return 0.5f * v * (1.0f + T);
}

// ---------------------------------------------------------------- init
__global__ void init_kernel(int* counts, int* cursors) {
  counts[threadIdx.x] = 0; cursors[threadIdx.x] = 0;
}

// ---------------------------------------------------------------- route (+ x -> bf16)
__global__ __launch_bounds__(256) void route_kernel(
    const float* __restrict__ x, const float* __restrict__ Wr,
    const float* __restrict__ br, short* __restrict__ xb,
    int* __restrict__ leafArr) {
  const int w = threadIdx.x >> 6, l = threadIdx.x & 63;
  const int tok = blockIdx.x * 4 + w;
  const float4* xr = (const float4*)(x + (size_t)tok * DMODEL);
  float4 a0 = xr[l * 2], a1 = xr[l * 2 + 1];

  union { bf16x8 v; short s[8]; } u;
  u.s[0] = f2bf(a0.x); u.s[1] = f2bf(a0.y); u.s[2] = f2bf(a0.z); u.s[3] = f2bf(a0.w);
  u.s[4] = f2bf(a1.x); u.s[5] = f2bf(a1.y); u.s[6] = f2bf(a1.z); u.s[7] = f2bf(a1.w);
  *((bf16x8*)(xb + (size_t)tok * DMODEL) + l) = u.v;

  int leaf = 0;
  for (int d = 0; d < 4; ++d) {
    const int node = (1 << d) - 1 + leaf;
    const float4* wr4 = (const float4*)(Wr + (size_t)node * DMODEL);
    float4 b0 = wr4[l * 2], b1v = wr4[l * 2 + 1];
    double s = (double)a0.x * (double)b0.x + (double)a0.y * (double)b0.y +
               (double)a0.z * (double)b0.z + (double)a0.w * (double)b0.w +
               (double)a1.x * (double)b1v.x + (double)a1.y * (double)b1v.y +
               (double)a1.z * (double)b1v.z + (double)a1.w * (double)b1v.w;
    for (int off = 32; off; off >>= 1) s += __shfl_xor(s, off);
    double sel = s + (double)br[node];
    leaf = leaf * 2 + (sel > 0.0 ? 1 : 0);
  }
  if (l == 0) leafArr[tok] = leaf;
}

// ---------------------------------------------------------------- count
__global__ __launch_bounds__(256) void count_kernel(
    const int* __restrict__ leafArr, int* __restrict__ counts,
    int* __restrict__ idx) {
  __shared__ int lcnt[NEXP];
  const int tid = threadIdx.x;
  if (tid < NEXP) lcnt[tid] = 0;
  __syncthreads();
  const int tok = blockIdx.x * 256 + tid;
  atomicAdd(&lcnt[leafArr[tok]], 1);
  __syncthreads();
  if (tid < NEXP && lcnt[tid]) atomicAdd(&counts[tid * CPAD], lcnt[tid]);
  for (int i = blockIdx.x * 256 + tid; i < PADN; i += gridDim.x * 256) idx[i] = 0;
}

// ---------------------------------------------------------------- scan (1 block)
__global__ void scan_kernel(const int* __restrict__ counts, int* poff, int* ntiles,
                            int* texp, int* tval) {
  if (threadIdx.x == 0) {
    int po = 0, nt = 0;
    for (int e = 0; e < NEXP; ++e) {
      poff[e] = po;
      const int c = counts[e * CPAD];
      const int t = (c + TM - 1) >> 8;
      for (int i = 0; i < t; ++i) {
        texp[nt] = e;
        int v = c - i * TM; if (v > TM) v = TM;
        tval[nt] = v;
        ++nt;
      }
      po += t << 8;
    }
    poff[NEXP] = po;
    *ntiles = nt;
  }
}

// ---------------------------------------------------------------- scatter
__global__ __launch_bounds__(256) void scatter_kernel(
    const int* __restrict__ leafArr, const int* __restrict__ poff,
    int* cursors, int* __restrict__ idx) {
  __shared__ int lcnt[NEXP], lbase[NEXP];
  const int tid = threadIdx.x;
  if (tid < NEXP) lcnt[tid] = 0;
  __syncthreads();
  const int tok = blockIdx.x * 256 + tid;
  const int e = leafArr[tok];
  const int r = atomicAdd(&lcnt[e], 1);
  __syncthreads();
  if (tid < NEXP) lbase[tid] = lcnt[tid] ? atomicAdd(&cursors[tid * CPAD], lcnt[tid]) : 0;
  __syncthreads();
  idx[poff[e] + lbase[e] + r] = tok;
}

// ---------------------------------------------------------------- transpose+convert
__global__ void tconv_kernel(const float* __restrict__ src, short* __restrict__ dst,
                             int R, int C) {
  __shared__ float tile[32][33];
  const int tx = threadIdx.x, ty = threadIdx.y;
  const int c0 = blockIdx.x * 32, r0 = blockIdx.y * 32;
  const size_t eoff = (size_t)blockIdx.z * R * C;
  for (int i = 0; i < 4; ++i)
    tile[ty + i * 8][tx] = src[eoff + (size_t)(r0 + ty + i * 8) * C + c0 + tx];
  __syncthreads();
  for (int i = 0; i < 4; ++i)
    dst[eoff + (size_t)(c0 + ty + i * 8) * R + r0 + tx] = f2bf(tile[tx][ty + i * 8]);
}

// ================================================================ GEMM core
// 256x256 tile, BK=64, 8 waves, SINGLE-buffered LDS (64 KB) -> 2 blocks/CU.
// Simple 2-barrier loop: stage -> vmcnt(0)+barrier -> 64 MFMA -> barrier.
// The staging drain is hidden by the CO-RESIDENT block's compute (m97/m114
// TLP regime) instead of by intra-block scheduling, which R1/R2 falsified.
// LDS chunk-XOR swizzle unchanged (0 measured bank conflicts): row r,
// 16B-chunk c at slot c^(r&7); fragment read applies (ch ^ (cc&7)).

#define STA1(ko)                                                               \
  { _Pragma("unroll") for (int j = 0; j < 4; ++j)                              \
      gload_lds16(aSrc[j] + (ko), lds + j * 4096 + w * 512); }

#define STB1(ko)                                                               \
  { _Pragma("unroll") for (int j = 0; j < 4; ++j)                              \
      gload_lds16(bSrc[j] + (ko), lds + 16384 + j * 4096 + w * 512); }

#define KLOOP_SIMPLE(NKT)                                                      \
  for (int kt = 0; kt < (NKT); ++kt) {                                         \
    STA1(kt << 6) STB1(kt << 6)                                                \
    asm volatile("s_waitcnt vmcnt(0)" ::: "memory");                           \
    __builtin_amdgcn_s_barrier();                                              \
    __builtin_amdgcn_s_setprio(1);                                             \
    _Pragma("unroll")                                                          \
    for (int ki = 0; ki < 2; ++ki) {                                           \
      const int sw_ = (((ki << 2) + q) ^ (cc & 7)) << 3;                       \
      bf16x8 af[8], bfv[4];                                                    \
      _Pragma("unroll")                                                        \
      for (int mi = 0; mi < 8; ++mi)                                           \
        af[mi] = *(const bf16x8*)(lds + (wr + mi * 16 + cc) * 64 + sw_);       \
      _Pragma("unroll")                                                        \
      for (int ni = 0; ni < 4; ++ni)                                           \
        bfv[ni] = *(const bf16x8*)(lds + 16384 + (wc + ni * 16 + cc) * 64 + sw_); \
      _Pragma("unroll")                                                        \
      for (int mi = 0; mi < 8; ++mi) {                                         \
        _Pragma("unroll")                                                      \
        for (int ni = 0; ni < 4; ++ni)                                         \
          acc[mi][ni] = __builtin_amdgcn_mfma_f32_16x16x32_bf16(               \
              af[mi], bfv[ni], acc[mi][ni], 0, 0, 0);                          \
      }                                                                        \
    }                                                                          \
    __builtin_amdgcn_s_setprio(0);                                             \
    __builtin_amdgcn_s_barrier();                                              \
  }

// ================================================================ GEMM1
__global__ __launch_bounds__(512, 4) void gemm1_kernel(
    const short* __restrict__ Xb, const short* __restrict__ W1T,
    const float* __restrict__ b1, const int* __restrict__ idx,
    const int* __restrict__ texp, const int* __restrict__ ntiles,
    short* __restrict__ H, int g0) {
  __shared__ short lds[32768];                 // A (16K shorts) | B (16K shorts)
  const int nb = gridDim.x, bid = blockIdx.x;
  int swz = bid;
  if ((nb & 7) == 0) { const int cpx = nb >> 3; swz = (bid & 7) * cpx + (bid >> 3); }
  const int lt = swz >> 3, cb = swz & 7;       // consecutive swz: same tile
  const int t = g0 + lt;
  if (t >= *ntiles) return;
  const int e = texp[t];
  const int c0 = cb * 256;

  const int tid = threadIdx.x, w = tid >> 6, lane = tid & 63;
  const int q = lane >> 4, cc = lane & 15;
  const int wr = (w >> 2) * 128, wc = (w & 3) * 64;
  const int srow = lane >> 3;
  const int skel = ((lane & 7) ^ srow) * 8;    // pre-swizzled global chunk

  // hoisted per-lane staging sources (gather resolved ONCE)
  const short* aSrc[4]; const short* bSrc[4];
#pragma unroll
  for (int j = 0; j < 4; ++j) {
    const int r = j * 64 + w * 8 + srow;
    const int gt = idx[t * TM + r];
    aSrc[j] = Xb + (size_t)gt * DMODEL + skel;
    bSrc[j] = W1T + ((size_t)e * HIDDEN + c0 + r) * DMODEL + skel;
  }

  f32x4 acc[8][4];
  const f32x4 zero = {0.f, 0.f, 0.f, 0.f};
#pragma unroll
  for (int mi = 0; mi < 8; ++mi)
#pragma unroll
    for (int ni = 0; ni < 4; ++ni) acc[mi][ni] = zero;

  KLOOP_SIMPLE(DMODEL / 64)

  // ---- epilogue: GELU -> swizzled LDS C-tile, in TWO 128-row halves (64 KB)
  short* Cs = lds;
  for (int h = 0; h < 2; ++h) {
    if ((w >> 2) == h) {                       // waves owning rows [h*128, h*128+128)
#pragma unroll
      for (int ni = 0; ni < 4; ++ni) {
        const int col = wc + ni * 16 + cc;
        const float bv = b1[e * HIDDEN + c0 + col];
#pragma unroll
        for (int mi = 0; mi < 8; ++mi) {
#pragma unroll
          for (int r = 0; r < 4; ++r) {
            const int lrow = mi * 16 + q * 4 + r;
            const float v = gelu_f(acc[mi][ni][r] + bv);
            Cs[lrow * 256 + ((((col >> 3) ^ (lrow & 15)) << 3) | (col & 7))] = f2bf(v);
          }
        }
      }
    }
    __syncthreads();
#pragma unroll
    for (int it = 0; it < 8; ++it) {
      const int lin = tid + it * 512;          // 0..4095
      const int row = lin >> 5;
      const int s = lin & 31;
      const bf16x8 vv = *(const bf16x8*)(Cs + row * 256 + s * 8);
      const int ch = s ^ (row & 15);
      *(bf16x8*)(H + ((size_t)lt * TM + h * 128 + row) * HIDDEN + c0 + (ch << 3)) = vv;
    }
    __syncthreads();
  }
}

// ================================================================ GEMM2
__global__ __launch_bounds__(512, 4) void gemm2_kernel(
    const short* __restrict__ H, const short* __restrict__ W2T,
    const float* __restrict__ b2, const int* __restrict__ idx,
    const int* __restrict__ texp, const int* __restrict__ tval,
    const int* __restrict__ ntiles, float* __restrict__ out, int g0) {
  __shared__ short lds[32768];
  const int nb = gridDim.x, bid = blockIdx.x;
  int swz = bid;
  if ((nb & 7) == 0) { const int cpx = nb >> 3; swz = (bid & 7) * cpx + (bid >> 3); }
  const int lt = swz >> 1, cb = swz & 1;       // both colblocks of a tile adjacent
  const int t = g0 + lt;
  if (t >= *ntiles) return;
  const int e = texp[t];
  const int c0 = cb * 256;

  const int tid = threadIdx.x, w = tid >> 6, lane = tid & 63;
  const int q = lane >> 4, cc = lane & 15;
  const int wr = (w >> 2) * 128, wc = (w & 3) * 64;
  const int srow = lane >> 3;
  const int skel = ((lane & 7) ^ srow) * 8;

  const short* aSrc[4]; const short* bSrc[4];
#pragma unroll
  for (int j = 0; j < 4; ++j) {
    const int r = j * 64 + w * 8 + srow;
    aSrc[j] = H + ((size_t)lt * TM + r) * HIDDEN + skel;
    bSrc[j] = W2T + ((size_t)e * DMODEL + c0 + r) * HIDDEN + skel;
  }

  f32x4 acc[8][4];
  const f32x4 zero = {0.f, 0.f, 0.f, 0.f};
#pragma unroll
  for (int mi = 0; mi < 8; ++mi)
#pragma unroll
    for (int ni = 0; ni < 4; ++ni) acc[mi][ni] = zero;

  KLOOP_SIMPLE(HIDDEN / 64)

  const int nv = tval[t];
#pragma unroll
  for (int ni = 0; ni < 4; ++ni) {
    const int col = c0 + wc + ni * 16 + cc;
    const float bv = b2[e * DMODEL + col];
#pragma unroll
    for (int mi = 0; mi < 8; ++mi) {
#pragma unroll
      for (int r = 0; r < 4; ++r) {
        const int row = wr + mi * 16 + q * 4 + r;
        if (row < nv) {
          const int tok = idx[t * TM + row];
          out[(size_t)tok * DMODEL + col] = acc[mi][ni][r] + bv;
        }
      }
    }
  }
}

// ---------------------------------------------------------------- host
extern "C" void kernel_launch(void* const* d_in, const int* in_sizes, int n_in,
                              void* d_out, int out_size, void* d_ws, size_t ws_size,
                              hipStream_t stream) {
  (void)in_sizes; (void)n_in; (void)out_size;
  const float* x  = (const float*)d_in[0];
  const float* Wr = (const float*)d_in[1];
  const float* br = (const float*)d_in[2];
  const float* W1 = (const float*)d_in[3];
  const float* b1 = (const float*)d_in[4];
  const float* W2 = (const float*)d_in[5];
  const float* b2 = (const float*)d_in[6];
  float* out = (float*)d_out;
  char* ws = (char*)d_ws;

  int* counts  = (int*)(ws + 0);
  int* cursors = (int*)(ws + 1024);
  int* poff    = (int*)(ws + 2048);
  int* ntiles  = (int*)(ws + 2304);
  int* texp    = (int*)(ws + 4096);
  int* tval    = (int*)(ws + 8192);
  int* leafA   = (int*)(ws + 16384);
  int* idx     = (int*)(ws + 16384 + 131072);

  const size_t MB32 = 33554432ull;
  short* Xb  = (short*)(ws + (1ull << 20));
  short* W1T = (short*)(ws + (1ull << 20) + MB32);
  short* W2T = (short*)(ws + (1ull << 20) + 2 * MB32);
  short* Hb  = (short*)(ws + (1ull << 20) + 3 * MB32);
  const size_t o_h = (1ull << 20) + 3 * MB32;
  const size_t perTile = (size_t)TM * HIDDEN * sizeof(short);   // 1 MB

  int TPG = MAXT;
  if (ws_size < o_h + (size_t)MAXT * perTile) {
    size_t avail = ws_size > o_h ? ws_size - o_h : 0;
    TPG = (int)(avail / perTile);
    TPG &= ~3;                   // keep TPG*2 a multiple of 8 (XCD swizzle)
    if (TPG < 4) TPG = 4;
  }
  const int ngroups = (MAXT + TPG - 1) / TPG;

  hipLaunchKernelGGL(init_kernel,    dim3(1),          dim3(256),   0, stream, counts, cursors);
  hipLaunchKernelGGL(route_kernel,   dim3(NTOK / 4),   dim3(256),   0, stream, x, Wr, br, Xb, leafA);
  hipLaunchKernelGGL(count_kernel,   dim3(NTOK / 256), dim3(256),   0, stream, leafA, counts, idx);
  hipLaunchKernelGGL(scan_kernel,    dim3(1),          dim3(64),    0, stream, counts, poff, ntiles, texp, tval);
  hipLaunchKernelGGL(scatter_kernel, dim3(NTOK / 256), dim3(256),   0, stream, leafA, poff, cursors, idx);
  hipLaunchKernelGGL(tconv_kernel,   dim3(64, 16, 16), dim3(32, 8), 0, stream, W1, W1T, DMODEL, HIDDEN);
  hipLaunchKernelGGL(tconv_kernel,   dim3(16, 64, 16), dim3(32, 8), 0, stream, W2, W2T, HIDDEN, DMODEL);

  for (int g = 0; g < ngroups; ++g) {
    hipLaunchKernelGGL(gemm1_kernel, dim3(TPG * 8), dim3(512), 0, stream,
                       Xb, W1T, b1, idx, texp, ntiles, Hb, g * TPG);
    hipLaunchKernelGGL(gemm2_kernel, dim3(TPG * 2), dim3(512), 0, stream,
                       Hb, W2T, b2, idx, texp, tval, ntiles, out, g * TPG);
  }
}

// Round 4
// 555.468 us; speedup vs baseline: 3.1486x; 3.1486x over previous
//
#include <hip/hip_runtime.h>
#include <math.h>

#define NTOK   32768
#define DMODEL 512
#define HIDDEN 2048
#define NEXP   16
#define TM     256             // token-tile (M)
#define MAXT   144             // sum_e ceil(c_e/256) <= 128+15, rounded to mult of 8
#define PADN   (MAXT * TM)
#define CPAD   16              // pad per-expert counters to one 64B line

typedef short bf16x8 __attribute__((ext_vector_type(8)));
typedef float f32x4  __attribute__((ext_vector_type(4)));

__device__ __forceinline__ short f2bf(float f) {
  union { float f; unsigned int u; } v; v.f = f;
  unsigned int r = v.u + 0x7FFFu + ((v.u >> 16) & 1u);   // RNE
  return (short)(r >> 16);
}

__device__ __forceinline__ void gload_lds16(const void* g, void* l) {
  __builtin_amdgcn_global_load_lds(
      (const __attribute__((address_space(1))) void*)g,
      (__attribute__((address_space(3))) void*)l, 16, 0, 0);
}

// tanh-form GELU, overflow-safe. |err| vs exact erf GELU < 4e-4.
__device__ __forceinline__ float gelu_f(float v) {
  const float u = v * (0.7978845608f + 0.0356774081f * v * v);
  const float au = fabsf(u);
  const float z = __expf(-2.0f * au);
  float T = (1.0f - z) / (1.0f + z);
  T = copysignf(T, u);
  return 0.5f * v * (1.0f + T);
}

// ---------------------------------------------------------------- init
__global__ void init_kernel(int* counts, int* cursors) {
  counts[threadIdx.x] = 0; cursors[threadIdx.x] = 0;
}

// ---------------------------------------------------------------- route (+ x -> bf16)
__global__ __launch_bounds__(256) void route_kernel(
    const float* __restrict__ x, const float* __restrict__ Wr,
    const float* __restrict__ br, short* __restrict__ xb,
    int* __restrict__ leafArr) {
  const int w = threadIdx.x >> 6, l = threadIdx.x & 63;
  const int tok = blockIdx.x * 4 + w;
  const float4* xr = (const float4*)(x + (size_t)tok * DMODEL);
  float4 a0 = xr[l * 2], a1 = xr[l * 2 + 1];

  union { bf16x8 v; short s[8]; } u;
  u.s[0] = f2bf(a0.x); u.s[1] = f2bf(a0.y); u.s[2] = f2bf(a0.z); u.s[3] = f2bf(a0.w);
  u.s[4] = f2bf(a1.x); u.s[5] = f2bf(a1.y); u.s[6] = f2bf(a1.z); u.s[7] = f2bf(a1.w);
  *((bf16x8*)(xb + (size_t)tok * DMODEL) + l) = u.v;

  int leaf = 0;
  for (int d = 0; d < 4; ++d) {
    const int node = (1 << d) - 1 + leaf;
    const float4* wr4 = (const float4*)(Wr + (size_t)node * DMODEL);
    float4 b0 = wr4[l * 2], b1v = wr4[l * 2 + 1];
    double s = (double)a0.x * (double)b0.x + (double)a0.y * (double)b0.y +
               (double)a0.z * (double)b0.z + (double)a0.w * (double)b0.w +
               (double)a1.x * (double)b1v.x + (double)a1.y * (double)b1v.y +
               (double)a1.z * (double)b1v.z + (double)a1.w * (double)b1v.w;
    for (int off = 32; off; off >>= 1) s += __shfl_xor(s, off);
    double sel = s + (double)br[node];
    leaf = leaf * 2 + (sel > 0.0 ? 1 : 0);
  }
  if (l == 0) leafArr[tok] = leaf;
}

// ---------------------------------------------------------------- count
__global__ __launch_bounds__(256) void count_kernel(
    const int* __restrict__ leafArr, int* __restrict__ counts,
    int* __restrict__ idx) {
  __shared__ int lcnt[NEXP];
  const int tid = threadIdx.x;
  if (tid < NEXP) lcnt[tid] = 0;
  __syncthreads();
  const int tok = blockIdx.x * 256 + tid;
  atomicAdd(&lcnt[leafArr[tok]], 1);
  __syncthreads();
  if (tid < NEXP && lcnt[tid]) atomicAdd(&counts[tid * CPAD], lcnt[tid]);
  for (int i = blockIdx.x * 256 + tid; i < PADN; i += gridDim.x * 256) idx[i] = 0;
}

// ---------------------------------------------------------------- scan (1 block)
__global__ void scan_kernel(const int* __restrict__ counts, int* poff, int* ntiles,
                            int* texp, int* tval) {
  if (threadIdx.x == 0) {
    int po = 0, nt = 0;
    for (int e = 0; e < NEXP; ++e) {
      poff[e] = po;
      const int c = counts[e * CPAD];
      const int t = (c + TM - 1) >> 8;
      for (int i = 0; i < t; ++i) {
        texp[nt] = e;
        int v = c - i * TM; if (v > TM) v = TM;
        tval[nt] = v;
        ++nt;
      }
      po += t << 8;
    }
    poff[NEXP] = po;
    *ntiles = nt;
  }
}

// ---------------------------------------------------------------- scatter
__global__ __launch_bounds__(256) void scatter_kernel(
    const int* __restrict__ leafArr, const int* __restrict__ poff,
    int* cursors, int* __restrict__ idx) {
  __shared__ int lcnt[NEXP], lbase[NEXP];
  const int tid = threadIdx.x;
  if (tid < NEXP) lcnt[tid] = 0;
  __syncthreads();
  const int tok = blockIdx.x * 256 + tid;
  const int e = leafArr[tok];
  const int r = atomicAdd(&lcnt[e], 1);
  __syncthreads();
  if (tid < NEXP) lbase[tid] = lcnt[tid] ? atomicAdd(&cursors[tid * CPAD], lcnt[tid]) : 0;
  __syncthreads();
  idx[poff[e] + lbase[e] + r] = tok;
}

// ---------------------------------------------------------------- transpose+convert
__global__ void tconv_kernel(const float* __restrict__ src, short* __restrict__ dst,
                             int R, int C) {
  __shared__ float tile[32][33];
  const int tx = threadIdx.x, ty = threadIdx.y;
  const int c0 = blockIdx.x * 32, r0 = blockIdx.y * 32;
  const size_t eoff = (size_t)blockIdx.z * R * C;
  for (int i = 0; i < 4; ++i)
    tile[ty + i * 8][tx] = src[eoff + (size_t)(r0 + ty + i * 8) * C + c0 + tx];
  __syncthreads();
  for (int i = 0; i < 4; ++i)
    dst[eoff + (size_t)(c0 + ty + i * 8) * R + r0 + tx] = f2bf(tile[tx][ty + i * 8]);
}

// ================================================================ GEMM1 core
// 256x256 tile, BK=64, 8 waves, double-buffered LDS (128 KB), 4 phases/K-tile,
// counted vmcnt(4) (R2 config: 112 VGPR, no spill, 0 bank conflicts).

#define STA2(pn, ko, J0)                                                       \
  { _Pragma("unroll") for (int j = (J0); j < (J0) + 2; ++j)                    \
      gload_lds16(aSrc[j] + (ko), lds + ((pn) << 14) + j * 4096 + w * 512); }

#define STB4(pn, ko)                                                           \
  { _Pragma("unroll") for (int j = 0; j < 4; ++j)                              \
      gload_lds16(bSrc[j] + (ko), lds + 32768 + ((pn) << 14) + j * 4096 + w * 512); }

#define PHASE(mh, ki, STAGE, POST)                                             \
  {                                                                            \
    bf16x8 af[4];                                                              \
    const int sw_ = ((((ki) << 2) + q) ^ (cc & 7)) << 3;                       \
    _Pragma("unroll")                                                          \
    for (int m2 = 0; m2 < 4; ++m2)                                             \
      af[m2] = *(const bf16x8*)(Ab + (wr + ((mh) * 4 + m2) * 16 + cc) * 64 + sw_); \
    if ((mh) == 0) {                                                           \
      _Pragma("unroll")                                                        \
      for (int ni = 0; ni < 4; ++ni)                                           \
        bfv[ni] = *(const bf16x8*)(Bb + (wc + ni * 16 + cc) * 64 + sw_);       \
    }                                                                          \
    STAGE                                                                      \
    __builtin_amdgcn_s_barrier();                                              \
    __builtin_amdgcn_s_setprio(1);                                             \
    _Pragma("unroll")                                                          \
    for (int m2 = 0; m2 < 4; ++m2) {                                           \
      _Pragma("unroll")                                                        \
      for (int ni = 0; ni < 4; ++ni)                                           \
        acc[(mh) * 4 + m2][ni] = __builtin_amdgcn_mfma_f32_16x16x32_bf16(      \
            af[m2], bfv[ni], acc[(mh) * 4 + m2][ni], 0, 0, 0);                 \
    }                                                                          \
    __builtin_amdgcn_s_setprio(0);                                             \
    POST                                                                       \
    __builtin_amdgcn_s_barrier();                                              \
  }

#define KLOOP(NKT)                                                             \
  STA2(0, 0, 0) STA2(0, 0, 2) STB4(0, 0) STB4(1, 64)                           \
  asm volatile("s_waitcnt vmcnt(4)" ::: "memory");                             \
  __builtin_amdgcn_s_barrier();                                                \
  for (int kt = 0; kt < (NKT); ++kt) {                                         \
    const int cur = kt & 1, pn = cur ^ 1;                                      \
    const short* Ab = lds + (cur << 14);                                       \
    const short* Bb = lds + 32768 + (cur << 14);                               \
    const int ko1 = (kt + 1) << 6, ko2 = (kt + 2) << 6;                        \
    const bool p1ok = kt + 1 < (NKT), p2ok = kt + 2 < (NKT);                   \
    PHASE(0, 0, if (p1ok) STA2(pn, ko1, 0), )                                  \
    PHASE(1, 0, if (p1ok) STA2(pn, ko1, 2), )                                  \
    PHASE(0, 1, , )                                                            \
    PHASE(1, 1, if (p2ok) STB4(cur, ko2),                                      \
          if (p2ok) { asm volatile("s_waitcnt vmcnt(4)" ::: "memory"); }       \
          else      { asm volatile("s_waitcnt vmcnt(0)" ::: "memory"); } )     \
  }

// ================================================================ GEMM1
__global__ __launch_bounds__(512, 2) void gemm1_kernel(
    const short* __restrict__ Xb, const short* __restrict__ W1T,
    const float* __restrict__ b1, const int* __restrict__ idx,
    const int* __restrict__ texp, const int* __restrict__ ntiles,
    short* __restrict__ H, int g0) {
  __shared__ short lds[65536];                 // A p0|p1 (16K shorts ea), B p0|p1
  const int nb = gridDim.x, bid = blockIdx.x;
  int swz = bid;
  if ((nb & 7) == 0) { const int cpx = nb >> 3; swz = (bid & 7) * cpx + (bid >> 3); }
  const int lt = swz >> 3, cb = swz & 7;       // consecutive swz: same tile
  const int t = g0 + lt;
  if (t >= *ntiles) return;
  const int e = texp[t];
  const int c0 = cb * 256;

  const int tid = threadIdx.x, w = tid >> 6, lane = tid & 63;
  const int q = lane >> 4, cc = lane & 15;
  const int wr = (w >> 2) * 128, wc = (w & 3) * 64;
  const int srow = lane >> 3;
  const int skel = ((lane & 7) ^ srow) * 8;    // pre-swizzled global chunk

  const short* aSrc[4]; const short* bSrc[4];
#pragma unroll
  for (int j = 0; j < 4; ++j) {
    const int r = j * 64 + w * 8 + srow;
    const int gt = idx[t * TM + r];
    aSrc[j] = Xb + (size_t)gt * DMODEL + skel;
    bSrc[j] = W1T + ((size_t)e * HIDDEN + c0 + r) * DMODEL + skel;
  }

  f32x4 acc[8][4];
  const f32x4 zero = {0.f, 0.f, 0.f, 0.f};
#pragma unroll
  for (int mi = 0; mi < 8; ++mi)
#pragma unroll
    for (int ni = 0; ni < 4; ++ni) acc[mi][ni] = zero;
  bf16x8 bfv[4];

  KLOOP(DMODEL / 64)

  // ---- epilogue: GELU -> swizzled LDS C-tile (256x256) -> 16B H stores
  short* Cs = lds;
#pragma unroll
  for (int ni = 0; ni < 4; ++ni) {
    const int col = wc + ni * 16 + cc;
    const float bv = b1[e * HIDDEN + c0 + col];
#pragma unroll
    for (int mi = 0; mi < 8; ++mi) {
#pragma unroll
      for (int r = 0; r < 4; ++r) {
        const int row = wr + mi * 16 + q * 4 + r;
        const float v = gelu_f(acc[mi][ni][r] + bv);
        Cs[row * 256 + ((((col >> 3) ^ (row & 15)) << 3) | (col & 7))] = f2bf(v);
      }
    }
  }
  __syncthreads();
#pragma unroll
  for (int it = 0; it < 16; ++it) {
    const int lin = tid + it * 512;            // 0..8191
    const int row = lin >> 5;
    const int s = lin & 31;
    const bf16x8 vv = *(const bf16x8*)(Cs + row * 256 + s * 8);
    const int ch = s ^ (row & 15);
    *(bf16x8*)(H + ((size_t)lt * TM + row) * HIDDEN + c0 + (ch << 3)) = vv;
  }
}

// ================================================================ GEMM2
// 256x128 tile (BN=128): 576 blocks -> makespan ~2.25 items/CU instead of the
// 288-block 2-full-item tail (32 blocks ran ~85us while 224 CUs idled).
// Wave tile 64x64 (acc[4][4]=64 regs). LDS 96 KB: A 2x16K shorts, B 2x8K.
// Same counted-vmcnt 4-phase skeleton; B = 2 gloads -> vmcnt(2).
#define G2STB2(pn, ko)                                                         \
  { _Pragma("unroll") for (int j = 0; j < 2; ++j)                              \
      gload_lds16(bSrc[j] + (ko), lds + 32768 + (pn) * 8192 + j * 4096 + w * 512); }

#define G2PHASE(mh, ki, STAGE, POST)                                           \
  {                                                                            \
    bf16x8 af[2];                                                              \
    const int sw_ = ((((ki) << 2) + q) ^ (cc & 7)) << 3;                       \
    _Pragma("unroll")                                                          \
    for (int m2 = 0; m2 < 2; ++m2)                                             \
      af[m2] = *(const bf16x8*)(Ab + (wr + ((mh) * 2 + m2) * 16 + cc) * 64 + sw_); \
    if ((mh) == 0) {                                                           \
      _Pragma("unroll")                                                        \
      for (int ni = 0; ni < 4; ++ni)                                           \
        bfv[ni] = *(const bf16x8*)(Bb + (wc + ni * 16 + cc) * 64 + sw_);       \
    }                                                                          \
    STAGE                                                                      \
    __builtin_amdgcn_s_barrier();                                              \
    __builtin_amdgcn_s_setprio(1);                                             \
    _Pragma("unroll")                                                          \
    for (int m2 = 0; m2 < 2; ++m2) {                                           \
      _Pragma("unroll")                                                        \
      for (int ni = 0; ni < 4; ++ni)                                           \
        acc[(mh) * 2 + m2][ni] = __builtin_amdgcn_mfma_f32_16x16x32_bf16(      \
            af[m2], bfv[ni], acc[(mh) * 2 + m2][ni], 0, 0, 0);                 \
    }                                                                          \
    __builtin_amdgcn_s_setprio(0);                                             \
    POST                                                                       \
    __builtin_amdgcn_s_barrier();                                              \
  }

__global__ __launch_bounds__(512, 2) void gemm2_kernel(
    const short* __restrict__ H, const short* __restrict__ W2T,
    const float* __restrict__ b2, const int* __restrict__ idx,
    const int* __restrict__ texp, const int* __restrict__ tval,
    const int* __restrict__ ntiles, float* __restrict__ out, int g0) {
  __shared__ short lds[49152];                 // A: 0|16384 (16K ea), B: 32768|40960 (8K ea)
  const int nb = gridDim.x, bid = blockIdx.x;
  int swz = bid;
  if ((nb & 7) == 0) { const int cpx = nb >> 3; swz = (bid & 7) * cpx + (bid >> 3); }
  const int lt = swz >> 2, cb = swz & 3;       // 4 colblocks of a tile adjacent (H L2-hot)
  const int t = g0 + lt;
  if (t >= *ntiles) return;
  const int e = texp[t];
  const int c0 = cb * 128;

  const int tid = threadIdx.x, w = tid >> 6, lane = tid & 63;
  const int q = lane >> 4, cc = lane & 15;
  const int wr = (w >> 1) * 64, wc = (w & 1) * 64;   // 4 m-waves x 2 n-waves
  const int srow = lane >> 3;
  const int skel = ((lane & 7) ^ srow) * 8;

  const short* aSrc[4]; const short* bSrc[2];
#pragma unroll
  for (int j = 0; j < 4; ++j) {
    const int r = j * 64 + w * 8 + srow;
    aSrc[j] = H + ((size_t)lt * TM + r) * HIDDEN + skel;
  }
#pragma unroll
  for (int j = 0; j < 2; ++j) {
    const int r = j * 64 + w * 8 + srow;
    bSrc[j] = W2T + ((size_t)e * DMODEL + c0 + r) * HIDDEN + skel;
  }

  f32x4 acc[4][4];
  const f32x4 zero = {0.f, 0.f, 0.f, 0.f};
#pragma unroll
  for (int mi = 0; mi < 4; ++mi)
#pragma unroll
    for (int ni = 0; ni < 4; ++ni) acc[mi][ni] = zero;
  bf16x8 bfv[4];

  // prologue: A(0) 4 + B(0) 2 + B(1) 2 = 8 in flight; keep B(1)'s 2
  STA2(0, 0, 0) STA2(0, 0, 2) G2STB2(0, 0) G2STB2(1, 64)
  asm volatile("s_waitcnt vmcnt(2)" ::: "memory");
  __builtin_amdgcn_s_barrier();

  for (int kt = 0; kt < HIDDEN / 64; ++kt) {
    const int cur = kt & 1, pn = cur ^ 1;
    const short* Ab = lds + (cur << 14);
    const short* Bb = lds + 32768 + cur * 8192;
    const int ko1 = (kt + 1) << 6, ko2 = (kt + 2) << 6;
    const bool p1ok = kt + 1 < HIDDEN / 64, p2ok = kt + 2 < HIDDEN / 64;
    G2PHASE(0, 0, if (p1ok) STA2(pn, ko1, 0), )
    G2PHASE(1, 0, if (p1ok) STA2(pn, ko1, 2), )
    G2PHASE(0, 1, , )
    G2PHASE(1, 1, if (p2ok) G2STB2(cur, ko2),
            if (p2ok) { asm volatile("s_waitcnt vmcnt(2)" ::: "memory"); }
            else      { asm volatile("s_waitcnt vmcnt(0)" ::: "memory"); } )
  }

  const int nv = tval[t];
#pragma unroll
  for (int ni = 0; ni < 4; ++ni) {
    const int col = c0 + wc + ni * 16 + cc;
    const float bv = b2[e * DMODEL + col];
#pragma unroll
    for (int mi = 0; mi < 4; ++mi) {
#pragma unroll
      for (int r = 0; r < 4; ++r) {
        const int row = wr + mi * 16 + q * 4 + r;
        if (row < nv) {
          const int tok = idx[t * TM + row];
          out[(size_t)tok * DMODEL + col] = acc[mi][ni][r] + bv;
        }
      }
    }
  }
}

// ---------------------------------------------------------------- host
extern "C" void kernel_launch(void* const* d_in, const int* in_sizes, int n_in,
                              void* d_out, int out_size, void* d_ws, size_t ws_size,
                              hipStream_t stream) {
  (void)in_sizes; (void)n_in; (void)out_size;
  const float* x  = (const float*)d_in[0];
  const float* Wr = (const float*)d_in[1];
  const float* br = (const float*)d_in[2];
  const float* W1 = (const float*)d_in[3];
  const float* b1 = (const float*)d_in[4];
  const float* W2 = (const float*)d_in[5];
  const float* b2 = (const float*)d_in[6];
  float* out = (float*)d_out;
  char* ws = (char*)d_ws;

  int* counts  = (int*)(ws + 0);
  int* cursors = (int*)(ws + 1024);
  int* poff    = (int*)(ws + 2048);
  int* ntiles  = (int*)(ws + 2304);
  int* texp    = (int*)(ws + 4096);
  int* tval    = (int*)(ws + 8192);
  int* leafA   = (int*)(ws + 16384);
  int* idx     = (int*)(ws + 16384 + 131072);

  const size_t MB32 = 33554432ull;
  short* Xb  = (short*)(ws + (1ull << 20));
  short* W1T = (short*)(ws + (1ull << 20) + MB32);
  short* W2T = (short*)(ws + (1ull << 20) + 2 * MB32);
  short* Hb  = (short*)(ws + (1ull << 20) + 3 * MB32);
  const size_t o_h = (1ull << 20) + 3 * MB32;
  const size_t perTile = (size_t)TM * HIDDEN * sizeof(short);   // 1 MB

  int TPG = MAXT;
  if (ws_size < o_h + (size_t)MAXT * perTile) {
    size_t avail = ws_size > o_h ? ws_size - o_h : 0;
    TPG = (int)(avail / perTile);
    TPG &= ~3;                   // keep TPG*4 / TPG*8 multiples of 8 (XCD swizzle)
    if (TPG < 4) TPG = 4;
  }
  const int ngroups = (MAXT + TPG - 1) / TPG;

  hipLaunchKernelGGL(init_kernel,    dim3(1),          dim3(256),   0, stream, counts, cursors);
  hipLaunchKernelGGL(route_kernel,   dim3(NTOK / 4),   dim3(256),   0, stream, x, Wr, br, Xb, leafA);
  hipLaunchKernelGGL(count_kernel,   dim3(NTOK / 256), dim3(256),   0, stream, leafA, counts, idx);
  hipLaunchKernelGGL(scan_kernel,    dim3(1),          dim3(64),    0, stream, counts, poff, ntiles, texp, tval);
  hipLaunchKernelGGL(scatter_kernel, dim3(NTOK / 256), dim3(256),   0, stream, leafA, poff, cursors, idx);
  hipLaunchKernelGGL(tconv_kernel,   dim3(64, 16, 16), dim3(32, 8), 0, stream, W1, W1T, DMODEL, HIDDEN);
  hipLaunchKernelGGL(tconv_kernel,   dim3(16, 64, 16), dim3(32, 8), 0, stream, W2, W2T, HIDDEN, DMODEL);

  for (int g = 0; g < ngroups; ++g) {
    hipLaunchKernelGGL(gemm1_kernel, dim3(TPG * 8), dim3(512), 0, stream,
                       Xb, W1T, b1, idx, texp, ntiles, Hb, g * TPG);
    hipLaunchKernelGGL(gemm2_kernel, dim3(TPG * 4), dim3(512), 0, stream,
                       Hb, W2T, b2, idx, texp, tval, ntiles, out, g * TPG);
  }
}